// Round 1
// baseline (561.822 us; speedup 1.0000x reference)
//
#include <hip/hip_runtime.h>
#include <math.h>

#define P 4096
#define NB 2
#define NROWS (NB * P)
#define THREADS 256
#define KPT 16                      // 4096 / 256 j's per thread
#define LOG_INV_P (-8.317766166719343f)   // log(1/4096)
#define THRESH 0.01f

// ws layout (floats): u[NROWS], v[NROWS], err[3], flag(int)
// d_out layout (floats): [0]=distance, [1..8192]=corr1, [8193..16384]=corr2

__global__ void init_kernel(float* __restrict__ ws, float* __restrict__ out) {
    int idx = blockIdx.x * blockDim.x + threadIdx.x;
    const int total = 2 * NROWS + 4;  // u, v, err[3], flag
    if (idx < total) ws[idx] = 0.0f;  // zero bit-pattern also zeroes the int flag
    if (idx == 0) out[0] = 0.0f;      // distance accumulator (d_out is poisoned)
}

// One block per output row. Computes pot[row] = LOG_INV_P - lse_j(w[j] - C(row,j)).
// WITH_ERR: also accumulates |pot_new - pot_old| into err_acc (Sinkhorn err).
// Frozen (no-op) once *flag is set, emulating the reference's `done` gating.
template <int WITH_ERR>
__global__ __launch_bounds__(THREADS) void lse_update(
    const float* __restrict__ ptsR,   // row-side points (NB, P, 3)
    const float* __restrict__ ptsC,   // col-side points (NB, P, 3)
    const float* __restrict__ w,      // other potential (NB, P)
    float* __restrict__ pot,          // potential to update (NB, P)
    const int* __restrict__ flag,
    float* __restrict__ err_acc)
{
    if (*flag) return;  // uniform across all threads
    __shared__ float sm[8];

    const int row = blockIdx.x;
    const int b = row >> 12;
    const int t = threadIdx.x;

    const float x0 = ptsR[row * 3 + 0];
    const float x1 = ptsR[row * 3 + 1];
    const float x2 = ptsR[row * 3 + 2];
    const float* __restrict__ yb = ptsC + b * (P * 3);
    const float* __restrict__ wb = w + b * P;

    float m[KPT];
#pragma unroll
    for (int k = 0; k < KPT; k++) {
        const int j = t + k * THREADS;
        const float d0 = x0 - yb[j * 3 + 0];
        const float d1 = x1 - yb[j * 3 + 1];
        const float d2 = x2 - yb[j * 3 + 2];
        const float c = d0 * d0 + d1 * d1 + d2 * d2;  // |x-y|^2 (P_EXP=2)
        m[k] = wb[j] - c;
    }

    // ---- pass 1: block max (for stable lse, matching jax.nn.logsumexp) ----
    float mx = m[0];
#pragma unroll
    for (int k = 1; k < KPT; k++) mx = fmaxf(mx, m[k]);
#pragma unroll
    for (int off = 32; off >= 1; off >>= 1)
        mx = fmaxf(mx, __shfl_down(mx, off, 64));
    const int wid = t >> 6;
    if ((t & 63) == 0) sm[wid] = mx;
    __syncthreads();
    if (t == 0) sm[4] = fmaxf(fmaxf(sm[0], sm[1]), fmaxf(sm[2], sm[3]));
    __syncthreads();
    mx = sm[4];

    // ---- pass 2: sum of exp(m - mx), from registers ----
    float s = 0.0f;
#pragma unroll
    for (int k = 0; k < KPT; k++) s += __expf(m[k] - mx);
#pragma unroll
    for (int off = 32; off >= 1; off >>= 1)
        s += __shfl_down(s, off, 64);
    if ((t & 63) == 0) sm[wid] = s;  // WAR on sm[0..3] ordered by the sync above
    __syncthreads();
    if (t == 0) {
        s = sm[0] + sm[1] + sm[2] + sm[3];
        const float lse = mx + __logf(s);
        const float pn = LOG_INV_P - lse;
        if (WITH_ERR) {
            const float d = fabsf(pn - pot[row]);
            atomicAdd(err_acc, d);
        }
        pot[row] = pn;
    }
}

__global__ void flag_update(const float* __restrict__ err_acc, int* __restrict__ flag) {
    if (!*flag && (*err_acc / (float)NB) < THRESH) *flag = 1;
}

// One block per row: corr_out[row] = argmax_j (potC[j] - C(row,j))  (first-index ties),
// optionally accumulating distance partials sum_j exp(potR[row] + m) * C.
template <int ACC_DIST>
__global__ __launch_bounds__(THREADS) void final_pass(
    const float* __restrict__ ptsR,
    const float* __restrict__ ptsC,
    const float* __restrict__ potR,
    const float* __restrict__ potC,
    float* __restrict__ corr_out,    // NROWS floats
    float* __restrict__ dist_out)
{
    __shared__ float smv[4];
    __shared__ int   smj[4];
    __shared__ float smd[4];

    const int row = blockIdx.x;
    const int b = row >> 12;
    const int t = threadIdx.x;

    const float x0 = ptsR[row * 3 + 0];
    const float x1 = ptsR[row * 3 + 1];
    const float x2 = ptsR[row * 3 + 2];
    const float ur = potR[row];
    const float* __restrict__ yb = ptsC + b * (P * 3);
    const float* __restrict__ wb = potC + b * P;

    float bv = -INFINITY;
    int bj = 0;
    float ds = 0.0f;
#pragma unroll
    for (int k = 0; k < KPT; k++) {
        const int j = t + k * THREADS;
        const float d0 = x0 - yb[j * 3 + 0];
        const float d1 = x1 - yb[j * 3 + 1];
        const float d2 = x2 - yb[j * 3 + 2];
        const float c = d0 * d0 + d1 * d1 + d2 * d2;
        const float m = wb[j] - c;
        if (m > bv) { bv = m; bj = j; }   // j increasing per thread -> first max
        if (ACC_DIST) ds += __expf(ur + m) * c;  // pi * C, raw exp like reference
    }
#pragma unroll
    for (int off = 32; off >= 1; off >>= 1) {
        const float ov = __shfl_down(bv, off, 64);
        const int   oj = __shfl_down(bj, off, 64);
        if (ov > bv || (ov == bv && oj < bj)) { bv = ov; bj = oj; }
        if (ACC_DIST) ds += __shfl_down(ds, off, 64);
    }
    const int wid = t >> 6;
    if ((t & 63) == 0) { smv[wid] = bv; smj[wid] = bj; smd[wid] = ds; }
    __syncthreads();
    if (t == 0) {
        bv = smv[0]; bj = smj[0];
#pragma unroll
        for (int i = 1; i < 4; i++) {
            if (smv[i] > bv || (smv[i] == bv && smj[i] < bj)) { bv = smv[i]; bj = smj[i]; }
        }
        corr_out[row] = (float)bj;
        if (ACC_DIST) {
            const float dsum = smd[0] + smd[1] + smd[2] + smd[3];
            atomicAdd(dist_out, dsum);
        }
    }
}

extern "C" void kernel_launch(void* const* d_in, const int* in_sizes, int n_in,
                              void* d_out, int out_size, void* d_ws, size_t ws_size,
                              hipStream_t stream) {
    const float* x = (const float*)d_in[0];   // (2, 4096, 3) f32
    const float* y = (const float*)d_in[1];   // (2, 4096, 3) f32
    float* out = (float*)d_out;               // 1 + 8192 + 8192 floats
    float* ws = (float*)d_ws;

    float* u = ws;
    float* v = ws + NROWS;
    float* err = ws + 2 * NROWS;              // err[0..2] for the 3 even iterations
    int* flag = (int*)(ws + 2 * NROWS + 3);

    const int init_total = 2 * NROWS + 4;
    init_kernel<<<(init_total + 255) / 256, 256, 0, stream>>>(ws, out);

    dim3 grid(NROWS), blk(THREADS);
    // i=0 (even): u update + err
    lse_update<1><<<grid, blk, 0, stream>>>(x, y, v, u, flag, &err[0]);
    flag_update<<<1, 1, 0, stream>>>(&err[0], flag);
    // i=1 (odd): v update
    lse_update<0><<<grid, blk, 0, stream>>>(y, x, u, v, flag, nullptr);
    // i=2 (even)
    lse_update<1><<<grid, blk, 0, stream>>>(x, y, v, u, flag, &err[1]);
    flag_update<<<1, 1, 0, stream>>>(&err[1], flag);
    // i=3 (odd)
    lse_update<0><<<grid, blk, 0, stream>>>(y, x, u, v, flag, nullptr);
    // i=4 (even): err gating after this is irrelevant to outputs
    lse_update<1><<<grid, blk, 0, stream>>>(x, y, v, u, flag, &err[2]);

    // Outputs: corr1 (+distance) from row orientation, corr2 from column orientation.
    final_pass<1><<<grid, blk, 0, stream>>>(x, y, u, v, out + 1, out);
    final_pass<0><<<grid, blk, 0, stream>>>(y, x, v, u, out + 1 + NROWS, nullptr);
}

// Round 2
// 250.361 us; speedup vs baseline: 2.2441x; 2.2441x over previous
//
#include <hip/hip_runtime.h>
#include <math.h>

#define P 4096
#define NB 2
#define NROWS (NB * P)
#define THREADS 256
#define R 16                          // rows per block
#define NCHUNK (P / THREADS)          // 16 j-chunks per pass
#define LOG_INV_P (-8.317766166719343f)   // log(1/4096)
#define THRESH 0.01f

// ws layout (floats): u[NROWS], v[NROWS], err[3], flag(int)
// d_out layout (floats): [0]=distance, [1..8192]=corr1, [8193..16384]=corr2

__global__ void init_kernel(float* __restrict__ ws, float* __restrict__ out) {
    int idx = blockIdx.x * blockDim.x + threadIdx.x;
    const int total = 2 * NROWS + 4;  // u, v, err[3], flag
    if (idx < total) ws[idx] = 0.0f;  // zero bit-pattern also zeroes the int flag
    if (idx == 0) out[0] = 0.0f;      // distance accumulator (d_out is poisoned)
}

// Block = R rows. Each thread owns j-strip {t, t+256, ...}; y/w loaded once per
// chunk and reused across all R rows from registers. Two-pass (max, then
// exp-sum) LSE, recomputing C from L1/L2-hot y instead of storing R*16 m's.
// pot[row] = LOG_INV_P - lse_j(w[j] - C(row,j)). Frozen once *flag set.
template <int WITH_ERR>
__global__ __launch_bounds__(THREADS) void lse_update(
    const float* __restrict__ ptsR,   // row-side points (NB, P, 3)
    const float* __restrict__ ptsC,   // col-side points (NB, P, 3)
    const float* __restrict__ w,      // other potential (NB, P)
    float* __restrict__ pot,          // potential to update (NB, P)
    const int* __restrict__ flag,
    float* __restrict__ err_acc)
{
    if (*flag) return;  // uniform
    __shared__ float red[4 * R];
    __shared__ float brow[R];

    const int row0 = blockIdx.x * R;
    const int b = row0 >> 12;         // R divides 4096 so no row0 straddle
    const int t = threadIdx.x;
    const int wid = t >> 6, lane = t & 63;

    const float* __restrict__ xb = ptsR + row0 * 3;
    const float* __restrict__ yb = ptsC + b * (P * 3);
    const float* __restrict__ wb = w + b * P;

    float xr0[R], xr1[R], xr2[R];
#pragma unroll
    for (int r = 0; r < R; r++) {
        xr0[r] = xb[r * 3 + 0];
        xr1[r] = xb[r * 3 + 1];
        xr2[r] = xb[r * 3 + 2];
    }

    // ---- pass 1: per-row max of m = w_j - |x_r - y_j|^2 ----
    float mx[R];
#pragma unroll
    for (int r = 0; r < R; r++) mx[r] = -INFINITY;

    for (int k = 0; k < NCHUNK; k++) {
        const int j = t + k * THREADS;
        const float y0 = yb[j * 3 + 0];
        const float y1 = yb[j * 3 + 1];
        const float y2 = yb[j * 3 + 2];
        const float wj = wb[j];
#pragma unroll
        for (int r = 0; r < R; r++) {
            const float d0 = xr0[r] - y0, d1 = xr1[r] - y1, d2 = xr2[r] - y2;
            const float c = d0 * d0 + d1 * d1 + d2 * d2;
            mx[r] = fmaxf(mx[r], wj - c);
        }
    }
#pragma unroll
    for (int r = 0; r < R; r++) {
        float v2 = mx[r];
#pragma unroll
        for (int off = 32; off >= 1; off >>= 1)
            v2 = fmaxf(v2, __shfl_down(v2, off, 64));
        if (lane == 0) red[wid * R + r] = v2;
    }
    __syncthreads();
    if (t < R)
        brow[t] = fmaxf(fmaxf(red[t], red[R + t]), fmaxf(red[2 * R + t], red[3 * R + t]));
    __syncthreads();
    float bmax[R];
#pragma unroll
    for (int r = 0; r < R; r++) bmax[r] = brow[r];

    // ---- pass 2: per-row sum of exp(m - bmax) (y re-read, L1/L2-hot) ----
    float s[R];
#pragma unroll
    for (int r = 0; r < R; r++) s[r] = 0.0f;

    for (int k = 0; k < NCHUNK; k++) {
        const int j = t + k * THREADS;
        const float y0 = yb[j * 3 + 0];
        const float y1 = yb[j * 3 + 1];
        const float y2 = yb[j * 3 + 2];
        const float wj = wb[j];
#pragma unroll
        for (int r = 0; r < R; r++) {
            const float d0 = xr0[r] - y0, d1 = xr1[r] - y1, d2 = xr2[r] - y2;
            const float c = d0 * d0 + d1 * d1 + d2 * d2;
            s[r] += __expf(wj - c - bmax[r]);
        }
    }
    __syncthreads();  // red[] reads above are done; safe to overwrite
#pragma unroll
    for (int r = 0; r < R; r++) {
        float v2 = s[r];
#pragma unroll
        for (int off = 32; off >= 1; off >>= 1)
            v2 += __shfl_down(v2, off, 64);
        if (lane == 0) red[wid * R + r] = v2;
    }
    __syncthreads();
    if (t < R) {
        const float ssum = red[t] + red[R + t] + red[2 * R + t] + red[3 * R + t];
        const float lse = brow[t] + __logf(ssum);
        const float pn = LOG_INV_P - lse;
        float d = 0.0f;
        if (WITH_ERR) d = fabsf(pn - pot[row0 + t]);
        pot[row0 + t] = pn;
        if (WITH_ERR) {
#pragma unroll
            for (int off = 8; off >= 1; off >>= 1)
                d += __shfl_down(d, off, 16);
            if (t == 0) atomicAdd(err_acc, d);
        }
    }
}

__global__ void flag_update(const float* __restrict__ err_acc, int* __restrict__ flag) {
    if (!*flag && (*err_acc / (float)NB) < THRESH) *flag = 1;
}

// Block = R rows: corr_out[row] = argmax_j (potC[j] - C(row,j)) (first-index
// ties), optionally accumulating distance sum_j exp(potR[row] + m) * C.
template <int ACC_DIST>
__global__ __launch_bounds__(THREADS) void final_pass(
    const float* __restrict__ ptsR,
    const float* __restrict__ ptsC,
    const float* __restrict__ potR,
    const float* __restrict__ potC,
    float* __restrict__ corr_out,    // NROWS floats
    float* __restrict__ dist_out)
{
    __shared__ float redv[4 * R];
    __shared__ int   redj[4 * R];
    __shared__ float redd[4];

    const int row0 = blockIdx.x * R;
    const int b = row0 >> 12;
    const int t = threadIdx.x;
    const int wid = t >> 6, lane = t & 63;

    const float* __restrict__ xb = ptsR + row0 * 3;
    const float* __restrict__ yb = ptsC + b * (P * 3);
    const float* __restrict__ wb = potC + b * P;

    float xr0[R], xr1[R], xr2[R], ur[R];
#pragma unroll
    for (int r = 0; r < R; r++) {
        xr0[r] = xb[r * 3 + 0];
        xr1[r] = xb[r * 3 + 1];
        xr2[r] = xb[r * 3 + 2];
        ur[r] = ACC_DIST ? potR[row0 + r] : 0.0f;
    }

    float bv[R];
    int bj[R];
    float ds = 0.0f;
#pragma unroll
    for (int r = 0; r < R; r++) { bv[r] = -INFINITY; bj[r] = 0; }

    for (int k = 0; k < NCHUNK; k++) {
        const int j = t + k * THREADS;
        const float y0 = yb[j * 3 + 0];
        const float y1 = yb[j * 3 + 1];
        const float y2 = yb[j * 3 + 2];
        const float wj = wb[j];
#pragma unroll
        for (int r = 0; r < R; r++) {
            const float d0 = xr0[r] - y0, d1 = xr1[r] - y1, d2 = xr2[r] - y2;
            const float c = d0 * d0 + d1 * d1 + d2 * d2;
            const float m = wj - c;
            const bool pgt = m > bv[r];      // strict >, j increasing -> first max
            bj[r] = pgt ? j : bj[r];
            bv[r] = pgt ? m : bv[r];
            if (ACC_DIST) ds += __expf(ur[r] + m) * c;  // pi*C, raw exp like ref
        }
    }
#pragma unroll
    for (int r = 0; r < R; r++) {
        float v2 = bv[r];
        int j2 = bj[r];
#pragma unroll
        for (int off = 32; off >= 1; off >>= 1) {
            const float ov = __shfl_down(v2, off, 64);
            const int   oj = __shfl_down(j2, off, 64);
            const bool take = (ov > v2) || (ov == v2 && oj < j2);
            v2 = take ? ov : v2;
            j2 = take ? oj : j2;
        }
        if (lane == 0) { redv[wid * R + r] = v2; redj[wid * R + r] = j2; }
    }
    if (ACC_DIST) {
#pragma unroll
        for (int off = 32; off >= 1; off >>= 1)
            ds += __shfl_down(ds, off, 64);
        if (lane == 0) redd[wid] = ds;
    }
    __syncthreads();
    if (t < R) {
        float v2 = redv[t];
        int j2 = redj[t];
#pragma unroll
        for (int w2 = 1; w2 < 4; w2++) {
            const float ov = redv[w2 * R + t];
            const int   oj = redj[w2 * R + t];
            const bool take = (ov > v2) || (ov == v2 && oj < j2);
            v2 = take ? ov : v2;
            j2 = take ? oj : j2;
        }
        corr_out[row0 + t] = (float)j2;
    }
    if (ACC_DIST && t == 0)
        atomicAdd(dist_out, redd[0] + redd[1] + redd[2] + redd[3]);
}

extern "C" void kernel_launch(void* const* d_in, const int* in_sizes, int n_in,
                              void* d_out, int out_size, void* d_ws, size_t ws_size,
                              hipStream_t stream) {
    const float* x = (const float*)d_in[0];   // (2, 4096, 3) f32
    const float* y = (const float*)d_in[1];   // (2, 4096, 3) f32
    float* out = (float*)d_out;               // 1 + 8192 + 8192 floats
    float* ws = (float*)d_ws;

    float* u = ws;
    float* v = ws + NROWS;
    float* err = ws + 2 * NROWS;              // err[0..2] for the 3 even iterations
    int* flag = (int*)(ws + 2 * NROWS + 3);

    const int init_total = 2 * NROWS + 4;
    init_kernel<<<(init_total + 255) / 256, 256, 0, stream>>>(ws, out);

    dim3 grid(NROWS / R), blk(THREADS);
    // i=0 (even): u update + err
    lse_update<1><<<grid, blk, 0, stream>>>(x, y, v, u, flag, &err[0]);
    flag_update<<<1, 1, 0, stream>>>(&err[0], flag);
    // i=1 (odd): v update
    lse_update<0><<<grid, blk, 0, stream>>>(y, x, u, v, flag, nullptr);
    // i=2 (even)
    lse_update<1><<<grid, blk, 0, stream>>>(x, y, v, u, flag, &err[1]);
    flag_update<<<1, 1, 0, stream>>>(&err[1], flag);
    // i=3 (odd)
    lse_update<0><<<grid, blk, 0, stream>>>(y, x, u, v, flag, nullptr);
    // i=4 (even): err gating after this is irrelevant to outputs
    lse_update<1><<<grid, blk, 0, stream>>>(x, y, v, u, flag, &err[2]);

    // Outputs: corr1 (+distance) from row orientation, corr2 from column orientation.
    final_pass<1><<<grid, blk, 0, stream>>>(x, y, u, v, out + 1, out);
    final_pass<0><<<grid, blk, 0, stream>>>(y, x, v, u, out + 1 + NROWS, nullptr);
}

// Round 3
// 243.878 us; speedup vs baseline: 2.3037x; 1.0266x over previous
//
#include <hip/hip_runtime.h>
#include <math.h>

#define P 4096
#define NB 2
#define NROWS (NB * P)
#define THREADS 512
#define NWAVE (THREADS / 64)
#define R 16                          // rows per block
#define NCHUNK (P / THREADS)          // 8 j-chunks per pass
#define NBLK (NROWS / R)              // 512 blocks per orientation
#define LOG_INV_P (-8.317766166719343f)   // log(1/4096)
// err semantics: frozen iff err_sum/NB < 0.01  <=>  err_sum < 0.02
#define ERR_T (0.02f)

// ws layout (floats): u[NROWS], v[NROWS], err[3] (+1 pad)
// d_out layout (floats): [0]=distance, [1..8192]=corr1, [8193..16384]=corr2

__global__ void init_kernel(float* __restrict__ ws, float* __restrict__ out) {
    int idx = blockIdx.x * blockDim.x + threadIdx.x;
    const int total = 2 * NROWS + 4;  // u, v, err[3], pad
    if (idx < total) ws[idx] = 0.0f;
    if (idx == 0) out[0] = 0.0f;      // distance accumulator (d_out is poisoned)
}

// Block = R rows. Each thread owns j-strip {t, t+512, ...}; y/w loaded once per
// chunk, reused for all R rows from registers. Two-pass (max, then exp-sum)
// LSE, bit-identical C = |x-y|^2 op order to keep argmax outputs exact.
// pot[row] = LOG_INV_P - lse_j(w[j] - C(row,j)).
// Sticky `done`: frozen iff (chk0 && *chk0<ERR_T) || (chk1 && *chk1<ERR_T);
// err values are finalized at the previous kernel boundary.
template <int WITH_ERR>
__global__ __launch_bounds__(THREADS) void lse_update(
    const float* __restrict__ ptsR,   // row-side points (NB, P, 3)
    const float* __restrict__ ptsC,   // col-side points (NB, P, 3)
    const float* __restrict__ w,      // other potential (NB, P)
    float* __restrict__ pot,          // potential to update (NB, P)
    float* __restrict__ err_acc,      // accumulate sum|delta| here (WITH_ERR)
    const float* __restrict__ chk0,   // earlier err slots for done-gating
    const float* __restrict__ chk1)
{
    bool frozen = false;
    if (chk0) frozen = frozen || (*chk0 < ERR_T);
    if (chk1) frozen = frozen || (*chk1 < ERR_T);
    if (frozen) return;  // uniform across grid

    __shared__ float red[NWAVE * R];
    __shared__ float brow[R];

    const int row0 = blockIdx.x * R;
    const int b = row0 >> 12;         // R divides 4096 so no straddle
    const int t = threadIdx.x;
    const int wid = t >> 6, lane = t & 63;

    const float* __restrict__ xb = ptsR + row0 * 3;
    const float* __restrict__ yb = ptsC + b * (P * 3);
    const float* __restrict__ wb = w + b * P;

    float xr0[R], xr1[R], xr2[R];
#pragma unroll
    for (int r = 0; r < R; r++) {
        xr0[r] = xb[r * 3 + 0];
        xr1[r] = xb[r * 3 + 1];
        xr2[r] = xb[r * 3 + 2];
    }

    // ---- pass 1: per-row max of m = w_j - |x_r - y_j|^2 ----
    float mx[R];
#pragma unroll
    for (int r = 0; r < R; r++) mx[r] = -INFINITY;

#pragma unroll
    for (int k = 0; k < NCHUNK; k++) {
        const int j = t + k * THREADS;
        const float y0 = yb[j * 3 + 0];
        const float y1 = yb[j * 3 + 1];
        const float y2 = yb[j * 3 + 2];
        const float wj = wb[j];
#pragma unroll
        for (int r = 0; r < R; r++) {
            const float d0 = xr0[r] - y0, d1 = xr1[r] - y1, d2 = xr2[r] - y2;
            const float c = d0 * d0 + d1 * d1 + d2 * d2;
            mx[r] = fmaxf(mx[r], wj - c);
        }
    }
#pragma unroll
    for (int r = 0; r < R; r++) {
        float v2 = mx[r];
#pragma unroll
        for (int off = 32; off >= 1; off >>= 1)
            v2 = fmaxf(v2, __shfl_down(v2, off, 64));
        if (lane == 0) red[wid * R + r] = v2;
    }
    __syncthreads();
    if (t < R) {
        float v2 = red[t];
#pragma unroll
        for (int w2 = 1; w2 < NWAVE; w2++) v2 = fmaxf(v2, red[w2 * R + t]);
        brow[t] = v2;
    }
    __syncthreads();
    float bmax[R];
#pragma unroll
    for (int r = 0; r < R; r++) bmax[r] = brow[r];

    // ---- pass 2: per-row sum of exp(m - bmax) (y re-read, L1/L2-hot) ----
    float s[R];
#pragma unroll
    for (int r = 0; r < R; r++) s[r] = 0.0f;

#pragma unroll
    for (int k = 0; k < NCHUNK; k++) {
        const int j = t + k * THREADS;
        const float y0 = yb[j * 3 + 0];
        const float y1 = yb[j * 3 + 1];
        const float y2 = yb[j * 3 + 2];
        const float wj = wb[j];
#pragma unroll
        for (int r = 0; r < R; r++) {
            const float d0 = xr0[r] - y0, d1 = xr1[r] - y1, d2 = xr2[r] - y2;
            const float c = d0 * d0 + d1 * d1 + d2 * d2;
            s[r] += __expf(wj - c - bmax[r]);
        }
    }
    // red[] reads all happened before the sync above pass-2; safe to rewrite.
#pragma unroll
    for (int r = 0; r < R; r++) {
        float v2 = s[r];
#pragma unroll
        for (int off = 32; off >= 1; off >>= 1)
            v2 += __shfl_down(v2, off, 64);
        if (lane == 0) red[wid * R + r] = v2;
    }
    __syncthreads();
    if (t < R) {
        float ssum = red[t];
#pragma unroll
        for (int w2 = 1; w2 < NWAVE; w2++) ssum += red[w2 * R + t];
        const float lse = brow[t] + __logf(ssum);
        const float pn = LOG_INV_P - lse;
        float d = 0.0f;
        if (WITH_ERR) d = fabsf(pn - pot[row0 + t]);
        pot[row0 + t] = pn;
        if (WITH_ERR) {
#pragma unroll
            for (int off = 8; off >= 1; off >>= 1)
                d += __shfl_down(d, off, 16);
            if (t == 0) atomicAdd(err_acc, d);
        }
    }
}

// Fused final pass: blocks [0, NBLK) do row-orientation (corr1 + distance),
// blocks [NBLK, 2*NBLK) do col-orientation (corr2). First-index tie-break.
__global__ __launch_bounds__(THREADS) void final_fused(
    const float* __restrict__ x,
    const float* __restrict__ y,
    const float* __restrict__ u,
    const float* __restrict__ v,
    float* __restrict__ out)          // [0]=dist, [1..]=corr1, [1+NROWS..]=corr2
{
    __shared__ float redv[NWAVE * R];
    __shared__ int   redj[NWAVE * R];
    __shared__ float redd[NWAVE];

    const bool isRow = blockIdx.x < NBLK;
    const int blk = isRow ? blockIdx.x : blockIdx.x - NBLK;
    const float* __restrict__ ptsR = isRow ? x : y;
    const float* __restrict__ ptsC = isRow ? y : x;
    const float* __restrict__ potR = isRow ? u : v;
    const float* __restrict__ potC = isRow ? v : u;
    float* __restrict__ corr_out = out + 1 + (isRow ? 0 : NROWS);

    const int row0 = blk * R;
    const int b = row0 >> 12;
    const int t = threadIdx.x;
    const int wid = t >> 6, lane = t & 63;

    const float* __restrict__ xb = ptsR + row0 * 3;
    const float* __restrict__ yb = ptsC + b * (P * 3);
    const float* __restrict__ wb = potC + b * P;

    float xr0[R], xr1[R], xr2[R], ur[R];
#pragma unroll
    for (int r = 0; r < R; r++) {
        xr0[r] = xb[r * 3 + 0];
        xr1[r] = xb[r * 3 + 1];
        xr2[r] = xb[r * 3 + 2];
        ur[r] = isRow ? potR[row0 + r] : 0.0f;
    }

    float bv[R];
    int bj[R];
    float ds = 0.0f;
#pragma unroll
    for (int r = 0; r < R; r++) { bv[r] = -INFINITY; bj[r] = 0; }

#pragma unroll
    for (int k = 0; k < NCHUNK; k++) {
        const int j = t + k * THREADS;
        const float y0 = yb[j * 3 + 0];
        const float y1 = yb[j * 3 + 1];
        const float y2 = yb[j * 3 + 2];
        const float wj = wb[j];
#pragma unroll
        for (int r = 0; r < R; r++) {
            const float d0 = xr0[r] - y0, d1 = xr1[r] - y1, d2 = xr2[r] - y2;
            const float c = d0 * d0 + d1 * d1 + d2 * d2;
            const float m = wj - c;
            const bool pgt = m > bv[r];      // strict >, j increasing -> first max
            bj[r] = pgt ? j : bj[r];
            bv[r] = pgt ? m : bv[r];
            if (isRow) ds += __expf(ur[r] + m) * c;  // pi*C, raw exp like ref
        }
    }
#pragma unroll
    for (int r = 0; r < R; r++) {
        float v2 = bv[r];
        int j2 = bj[r];
#pragma unroll
        for (int off = 32; off >= 1; off >>= 1) {
            const float ov = __shfl_down(v2, off, 64);
            const int   oj = __shfl_down(j2, off, 64);
            const bool take = (ov > v2) || (ov == v2 && oj < j2);
            v2 = take ? ov : v2;
            j2 = take ? oj : j2;
        }
        if (lane == 0) { redv[wid * R + r] = v2; redj[wid * R + r] = j2; }
    }
    if (isRow) {
#pragma unroll
        for (int off = 32; off >= 1; off >>= 1)
            ds += __shfl_down(ds, off, 64);
        if (lane == 0) redd[wid] = ds;
    }
    __syncthreads();
    if (t < R) {
        float v2 = redv[t];
        int j2 = redj[t];
#pragma unroll
        for (int w2 = 1; w2 < NWAVE; w2++) {
            const float ov = redv[w2 * R + t];
            const int   oj = redj[w2 * R + t];
            const bool take = (ov > v2) || (ov == v2 && oj < j2);
            v2 = take ? ov : v2;
            j2 = take ? oj : j2;
        }
        corr_out[row0 + t] = (float)j2;
    }
    if (isRow && t == 0) {
        float dsum = redd[0];
#pragma unroll
        for (int w2 = 1; w2 < NWAVE; w2++) dsum += redd[w2];
        atomicAdd(out, dsum);
    }
}

extern "C" void kernel_launch(void* const* d_in, const int* in_sizes, int n_in,
                              void* d_out, int out_size, void* d_ws, size_t ws_size,
                              hipStream_t stream) {
    const float* x = (const float*)d_in[0];   // (2, 4096, 3) f32
    const float* y = (const float*)d_in[1];   // (2, 4096, 3) f32
    float* out = (float*)d_out;               // 1 + 8192 + 8192 floats
    float* ws = (float*)d_ws;

    float* u = ws;
    float* v = ws + NROWS;
    float* err = ws + 2 * NROWS;              // err[0..2]

    const int init_total = 2 * NROWS + 4;
    init_kernel<<<(init_total + 255) / 256, 256, 0, stream>>>(ws, out);

    dim3 grid(NBLK), blk(THREADS);
    // i=0 (even): u update + err0; no done-gate yet
    lse_update<1><<<grid, blk, 0, stream>>>(x, y, v, u, &err[0], nullptr, nullptr);
    // i=1 (odd): v update; done = err0<T
    lse_update<0><<<grid, blk, 0, stream>>>(y, x, u, v, nullptr, &err[0], nullptr);
    // i=2 (even): u update + err1; done = err0<T
    lse_update<1><<<grid, blk, 0, stream>>>(x, y, v, u, &err[1], &err[0], nullptr);
    // i=3 (odd): v update; done = err0<T | err1<T (err1==0 if frozen -> consistent)
    lse_update<0><<<grid, blk, 0, stream>>>(y, x, u, v, nullptr, &err[0], &err[1]);
    // i=4 (even): u update; err unused by outputs
    lse_update<0><<<grid, blk, 0, stream>>>(x, y, v, u, nullptr, &err[0], &err[1]);

    // Fused outputs: corr1+distance (row orientation) and corr2 (col orientation).
    final_fused<<<dim3(2 * NBLK), blk, 0, stream>>>(x, y, u, v, out);
}

// Round 4
// 220.709 us; speedup vs baseline: 2.5455x; 1.1050x over previous
//
#include <hip/hip_runtime.h>
#include <math.h>

#define P 4096
#define NB 2
#define NROWS (NB * P)
#define THREADS 512
#define NWAVE (THREADS / 64)
#define R 8                           // rows per block (16 spilled: VGPR=128 + 116MB scratch writes in R3)
#define NCHUNK (P / THREADS)          // 8 j-chunks per pass
#define NBLK (NROWS / R)              // 1024 blocks per orientation
#define LOG_INV_P (-8.317766166719343f)   // log(1/4096)
// err semantics: frozen iff err_sum/NB < 0.01  <=>  err_sum < 0.02
#define ERR_T (0.02f)

// ws layout (floats): u[NROWS], v[NROWS], err[3] (+1 pad)
// u/v need NO init: i=0 (ZERO_W) treats v==0 and u_old==0 per reference init.
// d_out layout (floats): [0]=distance, [1..8192]=corr1, [8193..16384]=corr2

__global__ void init_kernel(float* __restrict__ err, float* __restrict__ out) {
    const int t = threadIdx.x;
    if (t < 4) err[t] = 0.0f;
    if (t == 4) out[0] = 0.0f;        // distance accumulator (d_out is poisoned)
}

// Block = R rows. Each thread owns j-strip {t, t+512, ...}; y/w loaded once per
// chunk, reused for all R rows from registers. Two-pass (max, then exp-sum)
// LSE matching jax.nn.logsumexp; per-row reduce order independent of R.
// pot[row] = LOG_INV_P - lse_j(w[j] - C(row,j)).
// ZERO_W: w treated as all-zero and old-pot treated as 0 (iteration 0 state).
// Sticky `done`: frozen iff any provided earlier err slot < ERR_T.
template <int WITH_ERR, int ZERO_W>
__global__ __launch_bounds__(THREADS, 4) void lse_update(
    const float* __restrict__ ptsR,   // row-side points (NB, P, 3)
    const float* __restrict__ ptsC,   // col-side points (NB, P, 3)
    const float* __restrict__ w,      // other potential (NB, P)
    float* __restrict__ pot,          // potential to update (NB, P)
    float* __restrict__ err_acc,      // accumulate sum|delta| here (WITH_ERR)
    const float* __restrict__ chk0,   // earlier err slots for done-gating
    const float* __restrict__ chk1)
{
    bool frozen = false;
    if (chk0) frozen = frozen || (*chk0 < ERR_T);
    if (chk1) frozen = frozen || (*chk1 < ERR_T);
    if (frozen) return;  // uniform across grid

    __shared__ float red[NWAVE * R];
    __shared__ float brow[R];

    const int row0 = blockIdx.x * R;
    const int b = row0 >> 12;         // R divides 4096 so no straddle
    const int t = threadIdx.x;
    const int wid = t >> 6, lane = t & 63;

    const float* __restrict__ xb = ptsR + row0 * 3;
    const float* __restrict__ yb = ptsC + b * (P * 3);
    const float* __restrict__ wb = w + b * P;

    float xr0[R], xr1[R], xr2[R];
#pragma unroll
    for (int r = 0; r < R; r++) {
        xr0[r] = xb[r * 3 + 0];
        xr1[r] = xb[r * 3 + 1];
        xr2[r] = xb[r * 3 + 2];
    }

    // ---- pass 1: per-row max of m = w_j - |x_r - y_j|^2 ----
    float mx[R];
#pragma unroll
    for (int r = 0; r < R; r++) mx[r] = -INFINITY;

#pragma unroll
    for (int k = 0; k < NCHUNK; k++) {
        const int j = t + k * THREADS;
        const float y0 = yb[j * 3 + 0];
        const float y1 = yb[j * 3 + 1];
        const float y2 = yb[j * 3 + 2];
        const float wj = ZERO_W ? 0.0f : wb[j];
#pragma unroll
        for (int r = 0; r < R; r++) {
            const float d0 = xr0[r] - y0, d1 = xr1[r] - y1, d2 = xr2[r] - y2;
            const float c = d0 * d0 + d1 * d1 + d2 * d2;
            mx[r] = fmaxf(mx[r], wj - c);
        }
    }
#pragma unroll
    for (int r = 0; r < R; r++) {
        float v2 = mx[r];
#pragma unroll
        for (int off = 32; off >= 1; off >>= 1)
            v2 = fmaxf(v2, __shfl_down(v2, off, 64));
        if (lane == 0) red[wid * R + r] = v2;
    }
    __syncthreads();
    if (t < R) {
        float v2 = red[t];
#pragma unroll
        for (int w2 = 1; w2 < NWAVE; w2++) v2 = fmaxf(v2, red[w2 * R + t]);
        brow[t] = v2;
    }
    __syncthreads();
    float bmax[R];
#pragma unroll
    for (int r = 0; r < R; r++) bmax[r] = brow[r];

    // ---- pass 2: per-row sum of exp(m - bmax) (y re-read, L1/L2-hot) ----
    float s[R];
#pragma unroll
    for (int r = 0; r < R; r++) s[r] = 0.0f;

#pragma unroll
    for (int k = 0; k < NCHUNK; k++) {
        const int j = t + k * THREADS;
        const float y0 = yb[j * 3 + 0];
        const float y1 = yb[j * 3 + 1];
        const float y2 = yb[j * 3 + 2];
        const float wj = ZERO_W ? 0.0f : wb[j];
#pragma unroll
        for (int r = 0; r < R; r++) {
            const float d0 = xr0[r] - y0, d1 = xr1[r] - y1, d2 = xr2[r] - y2;
            const float c = d0 * d0 + d1 * d1 + d2 * d2;
            s[r] += __expf(wj - c - bmax[r]);
        }
    }
    // red[] pass-1 reads completed before the sync above; safe to rewrite.
#pragma unroll
    for (int r = 0; r < R; r++) {
        float v2 = s[r];
#pragma unroll
        for (int off = 32; off >= 1; off >>= 1)
            v2 += __shfl_down(v2, off, 64);
        if (lane == 0) red[wid * R + r] = v2;
    }
    __syncthreads();
    if (t < R) {
        float ssum = red[t];
#pragma unroll
        for (int w2 = 1; w2 < NWAVE; w2++) ssum += red[w2 * R + t];
        const float lse = brow[t] + __logf(ssum);
        const float pn = LOG_INV_P - lse;
        float d = 0.0f;
        if (WITH_ERR) d = fabsf(pn - (ZERO_W ? 0.0f : pot[row0 + t]));
        pot[row0 + t] = pn;
        if (WITH_ERR) {
#pragma unroll
            for (int off = R / 2; off >= 1; off >>= 1)
                d += __shfl_down(d, off, R);
            if (t == 0) atomicAdd(err_acc, d);
        }
    }
}

// Fused final pass: blocks [0, NBLK) do row-orientation (corr1 + distance),
// blocks [NBLK, 2*NBLK) do col-orientation (corr2). First-index tie-break.
__global__ __launch_bounds__(THREADS, 4) void final_fused(
    const float* __restrict__ x,
    const float* __restrict__ y,
    const float* __restrict__ u,
    const float* __restrict__ v,
    float* __restrict__ out)          // [0]=dist, [1..]=corr1, [1+NROWS..]=corr2
{
    __shared__ float redv[NWAVE * R];
    __shared__ int   redj[NWAVE * R];
    __shared__ float redd[NWAVE];

    const bool isRow = blockIdx.x < NBLK;
    const int blk = isRow ? blockIdx.x : blockIdx.x - NBLK;
    const float* __restrict__ ptsR = isRow ? x : y;
    const float* __restrict__ ptsC = isRow ? y : x;
    const float* __restrict__ potR = isRow ? u : v;
    const float* __restrict__ potC = isRow ? v : u;
    float* __restrict__ corr_out = out + 1 + (isRow ? 0 : NROWS);

    const int row0 = blk * R;
    const int b = row0 >> 12;
    const int t = threadIdx.x;
    const int wid = t >> 6, lane = t & 63;

    const float* __restrict__ xb = ptsR + row0 * 3;
    const float* __restrict__ yb = ptsC + b * (P * 3);
    const float* __restrict__ wb = potC + b * P;

    float xr0[R], xr1[R], xr2[R], ur[R];
#pragma unroll
    for (int r = 0; r < R; r++) {
        xr0[r] = xb[r * 3 + 0];
        xr1[r] = xb[r * 3 + 1];
        xr2[r] = xb[r * 3 + 2];
        ur[r] = isRow ? potR[row0 + r] : 0.0f;
    }

    float bv[R];
    int bj[R];
    float ds = 0.0f;
#pragma unroll
    for (int r = 0; r < R; r++) { bv[r] = -INFINITY; bj[r] = 0; }

#pragma unroll
    for (int k = 0; k < NCHUNK; k++) {
        const int j = t + k * THREADS;
        const float y0 = yb[j * 3 + 0];
        const float y1 = yb[j * 3 + 1];
        const float y2 = yb[j * 3 + 2];
        const float wj = wb[j];
#pragma unroll
        for (int r = 0; r < R; r++) {
            const float d0 = xr0[r] - y0, d1 = xr1[r] - y1, d2 = xr2[r] - y2;
            const float c = d0 * d0 + d1 * d1 + d2 * d2;
            const float m = wj - c;
            const bool pgt = m > bv[r];      // strict >, j increasing -> first max
            bj[r] = pgt ? j : bj[r];
            bv[r] = pgt ? m : bv[r];
            if (isRow) ds += __expf(ur[r] + m) * c;  // pi*C, raw exp like ref
        }
    }
#pragma unroll
    for (int r = 0; r < R; r++) {
        float v2 = bv[r];
        int j2 = bj[r];
#pragma unroll
        for (int off = 32; off >= 1; off >>= 1) {
            const float ov = __shfl_down(v2, off, 64);
            const int   oj = __shfl_down(j2, off, 64);
            const bool take = (ov > v2) || (ov == v2 && oj < j2);
            v2 = take ? ov : v2;
            j2 = take ? oj : j2;
        }
        if (lane == 0) { redv[wid * R + r] = v2; redj[wid * R + r] = j2; }
    }
    if (isRow) {
#pragma unroll
        for (int off = 32; off >= 1; off >>= 1)
            ds += __shfl_down(ds, off, 64);
        if (lane == 0) redd[wid] = ds;
    }
    __syncthreads();
    if (t < R) {
        float v2 = redv[t];
        int j2 = redj[t];
#pragma unroll
        for (int w2 = 1; w2 < NWAVE; w2++) {
            const float ov = redv[w2 * R + t];
            const int   oj = redj[w2 * R + t];
            const bool take = (ov > v2) || (ov == v2 && oj < j2);
            v2 = take ? ov : v2;
            j2 = take ? oj : j2;
        }
        corr_out[row0 + t] = (float)j2;
    }
    if (isRow && t == 0) {
        float dsum = redd[0];
#pragma unroll
        for (int w2 = 1; w2 < NWAVE; w2++) dsum += redd[w2];
        atomicAdd(out, dsum);
    }
}

extern "C" void kernel_launch(void* const* d_in, const int* in_sizes, int n_in,
                              void* d_out, int out_size, void* d_ws, size_t ws_size,
                              hipStream_t stream) {
    const float* x = (const float*)d_in[0];   // (2, 4096, 3) f32
    const float* y = (const float*)d_in[1];   // (2, 4096, 3) f32
    float* out = (float*)d_out;               // 1 + 8192 + 8192 floats
    float* ws = (float*)d_ws;

    float* u = ws;
    float* v = ws + NROWS;
    float* err = ws + 2 * NROWS;              // err[0..2]

    init_kernel<<<1, 64, 0, stream>>>(err, out);

    dim3 grid(NBLK), blk(THREADS);
    // i=0 (even): u update + err0; v==0, u_old==0 (reference init state)
    lse_update<1, 1><<<grid, blk, 0, stream>>>(x, y, v, u, &err[0], nullptr, nullptr);
    // i=1 (odd): v update; done = err0<T
    lse_update<0, 0><<<grid, blk, 0, stream>>>(y, x, u, v, nullptr, &err[0], nullptr);
    // i=2 (even): u update + err1; done = err0<T
    lse_update<1, 0><<<grid, blk, 0, stream>>>(x, y, v, u, &err[1], &err[0], nullptr);
    // i=3 (odd): v update; done = err0<T | err1<T (err1==0 if frozen -> consistent)
    lse_update<0, 0><<<grid, blk, 0, stream>>>(y, x, u, v, nullptr, &err[0], &err[1]);
    // i=4 (even): u update; err unused by outputs
    lse_update<0, 0><<<grid, blk, 0, stream>>>(x, y, v, u, nullptr, &err[0], &err[1]);

    // Fused outputs: corr1+distance (row orientation) and corr2 (col orientation).
    final_fused<<<dim3(2 * NBLK), blk, 0, stream>>>(x, y, u, v, out);
}

// Round 5
// 182.214 us; speedup vs baseline: 3.0833x; 1.2113x over previous
//
#include <hip/hip_runtime.h>
#include <math.h>

#define P 4096
#define NB 2
#define NROWS (NB * P)                // 8192
#define THREADS 512
#define NWAVE (THREADS / 64)          // 8
#define R 8                           // rows per block
#define NCHUNK (P / THREADS)          // 8 j-chunks
#define NBLK (NROWS / R)              // 1024 blocks per orientation
#define LOG_INV_P (-8.317766166719343f)   // log(1/4096)
#define INV_P (0.000244140625f)           // 1/4096
// frozen iff err_sum/NB < 0.01  <=>  err_sum < 0.02
#define ERR_T (0.02f)

// ws float layout:
//   [0..8192)      u
//   [8192..16384)  v        (zero-inited: needed only if frozen at i=0)
//   [16384..16388) err0..2 + pad
//   [16640 + a*8192), a=0..5: SoA arrays xs0,xs1,xs2,ys0,ys1,ys2
#define WS_U   0
#define WS_V   NROWS
#define WS_ERR (2 * NROWS)
#define WS_SOA 16640

// d_out layout (floats): [0]=distance, [1..8192]=corr1, [8193..16384]=corr2

// SoA transpose of x,y + zero v/err/dist. grid 32x512 = 16384 threads.
__global__ void prep_kernel(const float* __restrict__ x, const float* __restrict__ y,
                            float* __restrict__ ws, float* __restrict__ out) {
    const int idx = blockIdx.x * blockDim.x + threadIdx.x;
    float* __restrict__ soa = ws + WS_SOA;
    if (idx < NROWS) {
        soa[0 * NROWS + idx] = x[idx * 3 + 0];
        soa[1 * NROWS + idx] = x[idx * 3 + 1];
        soa[2 * NROWS + idx] = x[idx * 3 + 2];
        ws[WS_V + idx] = 0.0f;
    } else {
        const int k = idx - NROWS;
        soa[3 * NROWS + k] = y[k * 3 + 0];
        soa[4 * NROWS + k] = y[k * 3 + 1];
        soa[5 * NROWS + k] = y[k * 3 + 2];
    }
    if (idx < 4) ws[WS_ERR + idx] = 0.0f;
    if (idx == 4) out[0] = 0.0f;      // distance accumulator (d_out is poisoned)
}

// Single-pass LSE (no max subtraction: m = w_j - C <= 0 structurally, no
// overflow possible; underflow only below e^-87, irrelevant for this data).
// pot[row] = LOG_INV_P - log(sum_j exp(w_j - C(row,j))).
// Block = R rows; y/w loaded once per chunk, reused for all R rows in regs.
// ZERO_W: w==0 and old-pot==0 (iteration-0 state). Sticky freeze via chk*.
template <int WITH_ERR, int ZERO_W>
__global__ __launch_bounds__(THREADS, 4) void lse_single(
    const float* __restrict__ rs0, const float* __restrict__ rs1,
    const float* __restrict__ rs2,                                  // row-side SoA
    const float* __restrict__ cs0, const float* __restrict__ cs1,
    const float* __restrict__ cs2,                                  // col-side SoA
    const float* __restrict__ w,      // other potential (NB*P)
    float* __restrict__ pot,          // potential to update (NB*P)
    float* __restrict__ err_acc,
    const float* __restrict__ chk0, const float* __restrict__ chk1)
{
    bool frozen = false;
    if (chk0) frozen = frozen || (*chk0 < ERR_T);
    if (chk1) frozen = frozen || (*chk1 < ERR_T);
    if (frozen) return;  // uniform across grid

    __shared__ float red[NWAVE * R];

    const int row0 = blockIdx.x * R;
    const int bofs = (row0 >> 12) << 12;   // batch offset in point index space
    const int t = threadIdx.x;
    const int wid = t >> 6, lane = t & 63;

    float xr0[R], xr1[R], xr2[R];
#pragma unroll
    for (int r = 0; r < R; r++) {
        xr0[r] = rs0[row0 + r];
        xr1[r] = rs1[row0 + r];
        xr2[r] = rs2[row0 + r];
    }
    float s[R];
#pragma unroll
    for (int r = 0; r < R; r++) s[r] = 0.0f;

#pragma unroll
    for (int k = 0; k < NCHUNK; k++) {
        const int j = bofs + t + k * THREADS;
        const float y0 = cs0[j], y1 = cs1[j], y2 = cs2[j];
        const float wj = ZERO_W ? 0.0f : w[j];
#pragma unroll
        for (int r = 0; r < R; r++) {
            const float d0 = xr0[r] - y0, d1 = xr1[r] - y1, d2 = xr2[r] - y2;
            const float c = d0 * d0 + d1 * d1 + d2 * d2;
            s[r] += __expf(wj - c);
        }
    }
#pragma unroll
    for (int r = 0; r < R; r++) {
        float v2 = s[r];
#pragma unroll
        for (int off = 32; off >= 1; off >>= 1)
            v2 += __shfl_down(v2, off, 64);
        if (lane == 0) red[wid * R + r] = v2;
    }
    __syncthreads();
    if (t < R) {
        float ssum = red[t];
#pragma unroll
        for (int w2 = 1; w2 < NWAVE; w2++) ssum += red[w2 * R + t];
        const float pn = LOG_INV_P - __logf(ssum);
        float d = 0.0f;
        if (WITH_ERR) d = fabsf(pn - (ZERO_W ? 0.0f : pot[row0 + t]));
        pot[row0 + t] = pn;
        if (WITH_ERR) {
#pragma unroll
            for (int off = R / 2; off >= 1; off >>= 1)
                d += __shfl_down(d, off, R);
            if (t == 0) atomicAdd(err_acc, d);
        }
    }
}

// Fused lse#5 + corr1 + distance. u_final == f(v_final) in ALL freeze cases
// (every even update follows the latest v), so this is ungated:
//   S_i = sum_j exp(v_j - C),  D_i = sum_j exp(v_j - C)*C
//   u_i = LOG_INV_P - log(S_i);  dist_i = (1/P) * D_i / S_i
//   corr1_i = argmax_j (v_j - C)   (first-index ties)
__global__ __launch_bounds__(THREADS, 4) void row_final(
    const float* __restrict__ rs0, const float* __restrict__ rs1,
    const float* __restrict__ rs2,                                  // x SoA
    const float* __restrict__ cs0, const float* __restrict__ cs1,
    const float* __restrict__ cs2,                                  // y SoA
    const float* __restrict__ v,      // final col potential
    float* __restrict__ u_out,        // final u written here
    float* __restrict__ corr1,
    float* __restrict__ dist)
{
    __shared__ float redS[NWAVE * R];
    __shared__ float redD[NWAVE * R];
    __shared__ float redv[NWAVE * R];
    __shared__ int   redj[NWAVE * R];

    const int row0 = blockIdx.x * R;
    const int bofs = (row0 >> 12) << 12;
    const int t = threadIdx.x;
    const int wid = t >> 6, lane = t & 63;

    float xr0[R], xr1[R], xr2[R];
#pragma unroll
    for (int r = 0; r < R; r++) {
        xr0[r] = rs0[row0 + r];
        xr1[r] = rs1[row0 + r];
        xr2[r] = rs2[row0 + r];
    }
    float S[R], D[R], bv[R];
    int bj[R];
#pragma unroll
    for (int r = 0; r < R; r++) { S[r] = 0.0f; D[r] = 0.0f; bv[r] = -INFINITY; bj[r] = 0; }

#pragma unroll
    for (int k = 0; k < NCHUNK; k++) {
        const int jj = t + k * THREADS;       // batch-local column index
        const int j = bofs + jj;
        const float y0 = cs0[j], y1 = cs1[j], y2 = cs2[j];
        const float wj = v[j];
#pragma unroll
        for (int r = 0; r < R; r++) {
            const float d0 = xr0[r] - y0, d1 = xr1[r] - y1, d2 = xr2[r] - y2;
            const float c = d0 * d0 + d1 * d1 + d2 * d2;
            const float m = wj - c;
            const float e = __expf(m);
            S[r] += e;
            D[r] += e * c;
            const bool pgt = m > bv[r];       // strict >, jj increasing -> first max
            bj[r] = pgt ? jj : bj[r];
            bv[r] = pgt ? m : bv[r];
        }
    }
#pragma unroll
    for (int r = 0; r < R; r++) {
        float sS = S[r], sD = D[r], v2 = bv[r];
        int j2 = bj[r];
#pragma unroll
        for (int off = 32; off >= 1; off >>= 1) {
            sS += __shfl_down(sS, off, 64);
            sD += __shfl_down(sD, off, 64);
            const float ov = __shfl_down(v2, off, 64);
            const int   oj = __shfl_down(j2, off, 64);
            const bool take = (ov > v2) || (ov == v2 && oj < j2);
            v2 = take ? ov : v2;
            j2 = take ? oj : j2;
        }
        if (lane == 0) {
            redS[wid * R + r] = sS;
            redD[wid * R + r] = sD;
            redv[wid * R + r] = v2;
            redj[wid * R + r] = j2;
        }
    }
    __syncthreads();
    if (t < R) {
        float sS = redS[t], sD = redD[t], v2 = redv[t];
        int j2 = redj[t];
#pragma unroll
        for (int w2 = 1; w2 < NWAVE; w2++) {
            sS += redS[w2 * R + t];
            sD += redD[w2 * R + t];
            const float ov = redv[w2 * R + t];
            const int   oj = redj[w2 * R + t];
            const bool take = (ov > v2) || (ov == v2 && oj < j2);
            v2 = take ? ov : v2;
            j2 = take ? oj : j2;
        }
        u_out[row0 + t] = LOG_INV_P - __logf(sS);
        corr1[row0 + t] = (float)j2;
        float dp = INV_P * sD / sS;
#pragma unroll
        for (int off = R / 2; off >= 1; off >>= 1)
            dp += __shfl_down(dp, off, R);
        if (t == 0) atomicAdd(dist, dp);
    }
}

// corr2_j = argmax_i (u_i - C(i,j)) -- row side = y points, col side = x/u.
__global__ __launch_bounds__(THREADS, 4) void col_final(
    const float* __restrict__ rs0, const float* __restrict__ rs1,
    const float* __restrict__ rs2,                                  // y SoA
    const float* __restrict__ cs0, const float* __restrict__ cs1,
    const float* __restrict__ cs2,                                  // x SoA
    const float* __restrict__ u,      // final row potential (from row_final)
    float* __restrict__ corr2)
{
    __shared__ float redv[NWAVE * R];
    __shared__ int   redj[NWAVE * R];

    const int row0 = blockIdx.x * R;
    const int bofs = (row0 >> 12) << 12;
    const int t = threadIdx.x;
    const int wid = t >> 6, lane = t & 63;

    float xr0[R], xr1[R], xr2[R];
#pragma unroll
    for (int r = 0; r < R; r++) {
        xr0[r] = rs0[row0 + r];
        xr1[r] = rs1[row0 + r];
        xr2[r] = rs2[row0 + r];
    }
    float bv[R];
    int bj[R];
#pragma unroll
    for (int r = 0; r < R; r++) { bv[r] = -INFINITY; bj[r] = 0; }

#pragma unroll
    for (int k = 0; k < NCHUNK; k++) {
        const int jj = t + k * THREADS;
        const int j = bofs + jj;
        const float y0 = cs0[j], y1 = cs1[j], y2 = cs2[j];
        const float wj = u[j];
#pragma unroll
        for (int r = 0; r < R; r++) {
            const float d0 = xr0[r] - y0, d1 = xr1[r] - y1, d2 = xr2[r] - y2;
            const float c = d0 * d0 + d1 * d1 + d2 * d2;
            const float m = wj - c;
            const bool pgt = m > bv[r];
            bj[r] = pgt ? jj : bj[r];
            bv[r] = pgt ? m : bv[r];
        }
    }
#pragma unroll
    for (int r = 0; r < R; r++) {
        float v2 = bv[r];
        int j2 = bj[r];
#pragma unroll
        for (int off = 32; off >= 1; off >>= 1) {
            const float ov = __shfl_down(v2, off, 64);
            const int   oj = __shfl_down(j2, off, 64);
            const bool take = (ov > v2) || (ov == v2 && oj < j2);
            v2 = take ? ov : v2;
            j2 = take ? oj : j2;
        }
        if (lane == 0) { redv[wid * R + r] = v2; redj[wid * R + r] = j2; }
    }
    __syncthreads();
    if (t < R) {
        float v2 = redv[t];
        int j2 = redj[t];
#pragma unroll
        for (int w2 = 1; w2 < NWAVE; w2++) {
            const float ov = redv[w2 * R + t];
            const int   oj = redj[w2 * R + t];
            const bool take = (ov > v2) || (ov == v2 && oj < j2);
            v2 = take ? ov : v2;
            j2 = take ? oj : j2;
        }
        corr2[row0 + t] = (float)j2;
    }
}

extern "C" void kernel_launch(void* const* d_in, const int* in_sizes, int n_in,
                              void* d_out, int out_size, void* d_ws, size_t ws_size,
                              hipStream_t stream) {
    const float* x = (const float*)d_in[0];   // (2, 4096, 3) f32
    const float* y = (const float*)d_in[1];   // (2, 4096, 3) f32
    float* out = (float*)d_out;               // 1 + 8192 + 8192 floats
    float* ws = (float*)d_ws;

    float* u = ws + WS_U;
    float* v = ws + WS_V;
    float* err = ws + WS_ERR;
    float* xs0 = ws + WS_SOA + 0 * NROWS;
    float* xs1 = ws + WS_SOA + 1 * NROWS;
    float* xs2 = ws + WS_SOA + 2 * NROWS;
    float* ys0 = ws + WS_SOA + 3 * NROWS;
    float* ys1 = ws + WS_SOA + 4 * NROWS;
    float* ys2 = ws + WS_SOA + 5 * NROWS;

    prep_kernel<<<32, 512, 0, stream>>>(x, y, ws, out);

    dim3 grid(NBLK), blk(THREADS);
    // i=0 (even): u = f(v==0), err0
    lse_single<1, 1><<<grid, blk, 0, stream>>>(xs0, xs1, xs2, ys0, ys1, ys2,
                                               v, u, &err[0], nullptr, nullptr);
    // i=1 (odd): v = g(u); frozen iff err0<T
    lse_single<0, 0><<<grid, blk, 0, stream>>>(ys0, ys1, ys2, xs0, xs1, xs2,
                                               u, v, nullptr, &err[0], nullptr);
    // i=2 (even): u = f(v), err1; frozen iff err0<T
    lse_single<1, 0><<<grid, blk, 0, stream>>>(xs0, xs1, xs2, ys0, ys1, ys2,
                                               v, u, &err[1], &err[0], nullptr);
    // i=3 (odd): v = g(u); frozen iff err0<T | err1<T (err1 stays 0 if frozen)
    lse_single<0, 0><<<grid, blk, 0, stream>>>(ys0, ys1, ys2, xs0, xs1, xs2,
                                               u, v, nullptr, &err[0], &err[1]);
    // i=4 fused into row_final (u_final == f(v_final) in every freeze case).
    row_final<<<grid, blk, 0, stream>>>(xs0, xs1, xs2, ys0, ys1, ys2,
                                        v, u, out + 1, out);
    col_final<<<grid, blk, 0, stream>>>(ys0, ys1, ys2, xs0, xs1, xs2,
                                        u, out + 1 + NROWS);
}

// Round 6
// 168.904 us; speedup vs baseline: 3.3263x; 1.0788x over previous
//
#include <hip/hip_runtime.h>
#include <math.h>

#define P 4096
#define NB 2
#define NROWS (NB * P)                // 8192
#define THREADS 512
#define NWAVE (THREADS / 64)          // 8
#define R 8                           // rows per block
#define NCHUNK (P / THREADS)          // 8 columns per thread
#define NBLK (NROWS / R)              // 1024 blocks per orientation
#define SQRT_LOG2E 1.2011224087864498f
// base-2 domain: pot2 = pot * log2(e); log2(1/4096) = -12 exactly.
#define LOG2_INV_P (-12.0f)
// frozen iff err_nat_sum < 0.02  <=>  sum|d_u2| < 0.02/ln2
#define ERR_T2 0.028853900817779268f
#define C_DIST 1.6922538540598323e-4f    // ln(2)/4096

// ws float layout:
//   [0..8192)      u2      (base-2 row potential)
//   [8192..16384)  v2      (zero-inited by prep: used if frozen at i=0)
//   [16384..16388) err0..2 + pad
//   [16640 + a*8192), a=0..7: SoA xs0,xs1,xs2,xn, ys0,ys1,ys2,yn
//     xs = x*s, xn = |xs|^2 ; ys = 2*s*y, yn = |s*y|^2  (s = sqrt(log2e))
//     => m2 = w2 - xn - yn + <xs,ys> = log2e * (w - |x-y|^2)
#define WS_U   0
#define WS_V   NROWS
#define WS_ERR (2 * NROWS)
#define WS_SOA 16640

// d_out layout (floats): [0]=distance, [1..8192]=corr1, [8193..16384]=corr2

__device__ __forceinline__ float exp2_hw(float x) {
    float r;
    asm("v_exp_f32 %0, %1" : "=v"(r) : "v"(x));   // 2^x, single instr
    return r;
}

__global__ void prep_kernel(const float* __restrict__ x, const float* __restrict__ y,
                            float* __restrict__ ws, float* __restrict__ out) {
    const int idx = blockIdx.x * blockDim.x + threadIdx.x;  // 0..16383
    float* __restrict__ soa = ws + WS_SOA;
    if (idx < NROWS) {
        const float a0 = x[idx * 3 + 0] * SQRT_LOG2E;
        const float a1 = x[idx * 3 + 1] * SQRT_LOG2E;
        const float a2 = x[idx * 3 + 2] * SQRT_LOG2E;
        soa[0 * NROWS + idx] = a0;
        soa[1 * NROWS + idx] = a1;
        soa[2 * NROWS + idx] = a2;
        soa[3 * NROWS + idx] = a0 * a0 + a1 * a1 + a2 * a2;
        ws[WS_V + idx] = 0.0f;
    } else {
        const int k = idx - NROWS;
        const float a0 = y[k * 3 + 0] * SQRT_LOG2E;
        const float a1 = y[k * 3 + 1] * SQRT_LOG2E;
        const float a2 = y[k * 3 + 2] * SQRT_LOG2E;
        soa[4 * NROWS + k] = a0 + a0;   // 2*s*y for the fma dot (factor 2 baked in)
        soa[5 * NROWS + k] = a1 + a1;
        soa[6 * NROWS + k] = a2 + a2;
        soa[7 * NROWS + k] = a0 * a0 + a1 * a1 + a2 * a2;  // s^2|y|^2
    }
    if (idx < 4) ws[WS_ERR + idx] = 0.0f;
    if (idx == 4) out[0] = 0.0f;        // distance accumulator (d_out is poisoned)
}

// pot2[row] = -12 - log2( sum_j exp2( w2_j - cn_j - rn_r + <rc_r, cc_j> ) )
// All of the thread's column strip (coords + a_k = w2-cn) is loaded into
// registers up-front -> inner 64 iterations are pure VALU (no memory stalls).
// ZERO_W: w2==0 and old-pot==0 (iteration-0 state). Sticky freeze via chk*.
template <int WITH_ERR, int ZERO_W>
__global__ __launch_bounds__(THREADS, 4) void lse_single(
    const float* __restrict__ rc0, const float* __restrict__ rc1,
    const float* __restrict__ rc2, const float* __restrict__ rn,   // row-side SoA
    const float* __restrict__ cc0, const float* __restrict__ cc1,
    const float* __restrict__ cc2, const float* __restrict__ cn,   // col-side SoA
    const float* __restrict__ w2,     // other potential (base-2)
    float* __restrict__ pot2,         // potential to update (base-2)
    float* __restrict__ err_acc,
    const float* __restrict__ chk0, const float* __restrict__ chk1)
{
    bool frozen = false;
    if (chk0) frozen = frozen || (*chk0 < ERR_T2);
    if (chk1) frozen = frozen || (*chk1 < ERR_T2);
    if (frozen) return;  // uniform across grid

    __shared__ float red[NWAVE * R];

    const int row0 = blockIdx.x * R;
    const int bofs = (row0 >> 12) << 12;
    const int t = threadIdx.x;
    const int wid = t >> 6, lane = t & 63;
    const int jbase = bofs + t;

    float r0[R], r1[R], r2[R], rnm[R];
#pragma unroll
    for (int r = 0; r < R; r++) {
        r0[r] = rc0[row0 + r];
        r1[r] = rc1[row0 + r];
        r2[r] = rc2[row0 + r];
        rnm[r] = rn[row0 + r];
    }
    float c0[NCHUNK], c1[NCHUNK], c2[NCHUNK], a[NCHUNK];
#pragma unroll
    for (int k = 0; k < NCHUNK; k++) {
        const int j = jbase + k * THREADS;
        c0[k] = cc0[j];
        c1[k] = cc1[j];
        c2[k] = cc2[j];
        a[k] = (ZERO_W ? 0.0f : w2[j]) - cn[j];
    }

    float s[R];
#pragma unroll
    for (int r = 0; r < R; r++) s[r] = 0.0f;

#pragma unroll
    for (int k = 0; k < NCHUNK; k++) {
#pragma unroll
        for (int r = 0; r < R; r++) {
            const float b = a[k] - rnm[r];
            const float m2 = fmaf(c0[k], r0[r], fmaf(c1[k], r1[r], fmaf(c2[k], r2[r], b)));
            s[r] += exp2_hw(m2);
        }
    }
#pragma unroll
    for (int r = 0; r < R; r++) {
        float v2 = s[r];
#pragma unroll
        for (int off = 32; off >= 1; off >>= 1)
            v2 += __shfl_down(v2, off, 64);
        if (lane == 0) red[wid * R + r] = v2;
    }
    __syncthreads();
    if (t < R) {
        float ssum = red[t];
#pragma unroll
        for (int w = 1; w < NWAVE; w++) ssum += red[w * R + t];
        const float pn = LOG2_INV_P - __log2f(ssum);
        float d = 0.0f;
        if (WITH_ERR) d = fabsf(pn - (ZERO_W ? 0.0f : pot2[row0 + t]));
        pot2[row0 + t] = pn;
        if (WITH_ERR) {
#pragma unroll
            for (int off = R / 2; off >= 1; off >>= 1)
                d += __shfl_down(d, off, R);
            if (t == 0) atomicAdd(err_acc, d);
        }
    }
}

// Fused lse#5 + corr1 + distance (u_final == f(v_final) in all freeze cases):
//   S_i = sum_j e_ij,  D2_i = sum_j e_ij*(v2_j - m2_ij)   [= log2e * C]
//   u2_i = -12 - log2(S_i);  dist_i = (ln2/P) * D2_i / S_i
//   corr1_i = argmax_j m2_ij (first-index ties; monotone in reference pi)
__global__ __launch_bounds__(THREADS, 4) void row_final(
    const float* __restrict__ rc0, const float* __restrict__ rc1,
    const float* __restrict__ rc2, const float* __restrict__ rn,   // x SoA
    const float* __restrict__ cc0, const float* __restrict__ cc1,
    const float* __restrict__ cc2, const float* __restrict__ cn,   // y SoA
    const float* __restrict__ w2,     // final v2
    float* __restrict__ u2_out,
    float* __restrict__ corr1,
    float* __restrict__ dist)
{
    __shared__ float redS[NWAVE * R];
    __shared__ float redD[NWAVE * R];
    __shared__ float redv[NWAVE * R];
    __shared__ int   redj[NWAVE * R];

    const int row0 = blockIdx.x * R;
    const int bofs = (row0 >> 12) << 12;
    const int t = threadIdx.x;
    const int wid = t >> 6, lane = t & 63;
    const int jbase = bofs + t;

    float r0[R], r1[R], r2[R], rnm[R];
#pragma unroll
    for (int r = 0; r < R; r++) {
        r0[r] = rc0[row0 + r];
        r1[r] = rc1[row0 + r];
        r2[r] = rc2[row0 + r];
        rnm[r] = rn[row0 + r];
    }
    float c0[NCHUNK], c1[NCHUNK], c2[NCHUNK], a[NCHUNK], wv[NCHUNK];
#pragma unroll
    for (int k = 0; k < NCHUNK; k++) {
        const int j = jbase + k * THREADS;
        c0[k] = cc0[j];
        c1[k] = cc1[j];
        c2[k] = cc2[j];
        wv[k] = w2[j];
        a[k] = wv[k] - cn[j];
    }

    float S[R], D[R], bv[R];
    int bj[R];
#pragma unroll
    for (int r = 0; r < R; r++) { S[r] = 0.0f; D[r] = 0.0f; bv[r] = -INFINITY; bj[r] = 0; }

#pragma unroll
    for (int k = 0; k < NCHUNK; k++) {
#pragma unroll
        for (int r = 0; r < R; r++) {
            const float b = a[k] - rnm[r];
            const float m2 = fmaf(c0[k], r0[r], fmaf(c1[k], r1[r], fmaf(c2[k], r2[r], b)));
            const float e = exp2_hw(m2);
            S[r] += e;
            D[r] = fmaf(e, wv[k] - m2, D[r]);     // (v2 - m2) = log2e * C >= 0
            const bool pgt = m2 > bv[r];          // strict >, k ascending -> first max
            bj[r] = pgt ? (t + k * THREADS) : bj[r];
            bv[r] = pgt ? m2 : bv[r];
        }
    }
#pragma unroll
    for (int r = 0; r < R; r++) {
        float sS = S[r], sD = D[r], v2 = bv[r];
        int j2 = bj[r];
#pragma unroll
        for (int off = 32; off >= 1; off >>= 1) {
            sS += __shfl_down(sS, off, 64);
            sD += __shfl_down(sD, off, 64);
            const float ov = __shfl_down(v2, off, 64);
            const int   oj = __shfl_down(j2, off, 64);
            const bool take = (ov > v2) || (ov == v2 && oj < j2);
            v2 = take ? ov : v2;
            j2 = take ? oj : j2;
        }
        if (lane == 0) {
            redS[wid * R + r] = sS;
            redD[wid * R + r] = sD;
            redv[wid * R + r] = v2;
            redj[wid * R + r] = j2;
        }
    }
    __syncthreads();
    if (t < R) {
        float sS = redS[t], sD = redD[t], v2 = redv[t];
        int j2 = redj[t];
#pragma unroll
        for (int w = 1; w < NWAVE; w++) {
            sS += redS[w * R + t];
            sD += redD[w * R + t];
            const float ov = redv[w * R + t];
            const int   oj = redj[w * R + t];
            const bool take = (ov > v2) || (ov == v2 && oj < j2);
            v2 = take ? ov : v2;
            j2 = take ? oj : j2;
        }
        u2_out[row0 + t] = LOG2_INV_P - __log2f(sS);
        corr1[row0 + t] = (float)j2;
        float dp = C_DIST * sD / sS;
#pragma unroll
        for (int off = R / 2; off >= 1; off >>= 1)
            dp += __shfl_down(dp, off, R);
        if (t == 0) atomicAdd(dist, dp);
    }
}

// corr2_j = argmax_i m2_ij : rows = y points, cols = x points (+ final u2).
__global__ __launch_bounds__(THREADS, 4) void col_final(
    const float* __restrict__ rc0, const float* __restrict__ rc1,
    const float* __restrict__ rc2, const float* __restrict__ rn,   // y SoA
    const float* __restrict__ cc0, const float* __restrict__ cc1,
    const float* __restrict__ cc2, const float* __restrict__ cn,   // x SoA
    const float* __restrict__ w2,     // final u2
    float* __restrict__ corr2)
{
    __shared__ float redv[NWAVE * R];
    __shared__ int   redj[NWAVE * R];

    const int row0 = blockIdx.x * R;
    const int bofs = (row0 >> 12) << 12;
    const int t = threadIdx.x;
    const int wid = t >> 6, lane = t & 63;
    const int jbase = bofs + t;

    float r0[R], r1[R], r2[R], rnm[R];
#pragma unroll
    for (int r = 0; r < R; r++) {
        r0[r] = rc0[row0 + r];
        r1[r] = rc1[row0 + r];
        r2[r] = rc2[row0 + r];
        rnm[r] = rn[row0 + r];
    }
    float c0[NCHUNK], c1[NCHUNK], c2[NCHUNK], a[NCHUNK];
#pragma unroll
    for (int k = 0; k < NCHUNK; k++) {
        const int j = jbase + k * THREADS;
        c0[k] = cc0[j];
        c1[k] = cc1[j];
        c2[k] = cc2[j];
        a[k] = w2[j] - cn[j];
    }

    float bv[R];
    int bj[R];
#pragma unroll
    for (int r = 0; r < R; r++) { bv[r] = -INFINITY; bj[r] = 0; }

#pragma unroll
    for (int k = 0; k < NCHUNK; k++) {
#pragma unroll
        for (int r = 0; r < R; r++) {
            const float b = a[k] - rnm[r];
            const float m2 = fmaf(c0[k], r0[r], fmaf(c1[k], r1[r], fmaf(c2[k], r2[r], b)));
            const bool pgt = m2 > bv[r];
            bj[r] = pgt ? (t + k * THREADS) : bj[r];
            bv[r] = pgt ? m2 : bv[r];
        }
    }
#pragma unroll
    for (int r = 0; r < R; r++) {
        float v2 = bv[r];
        int j2 = bj[r];
#pragma unroll
        for (int off = 32; off >= 1; off >>= 1) {
            const float ov = __shfl_down(v2, off, 64);
            const int   oj = __shfl_down(j2, off, 64);
            const bool take = (ov > v2) || (ov == v2 && oj < j2);
            v2 = take ? ov : v2;
            j2 = take ? oj : j2;
        }
        if (lane == 0) { redv[wid * R + r] = v2; redj[wid * R + r] = j2; }
    }
    __syncthreads();
    if (t < R) {
        float v2 = redv[t];
        int j2 = redj[t];
#pragma unroll
        for (int w = 1; w < NWAVE; w++) {
            const float ov = redv[w * R + t];
            const int   oj = redj[w * R + t];
            const bool take = (ov > v2) || (ov == v2 && oj < j2);
            v2 = take ? ov : v2;
            j2 = take ? oj : j2;
        }
        corr2[row0 + t] = (float)j2;
    }
}

extern "C" void kernel_launch(void* const* d_in, const int* in_sizes, int n_in,
                              void* d_out, int out_size, void* d_ws, size_t ws_size,
                              hipStream_t stream) {
    const float* x = (const float*)d_in[0];   // (2, 4096, 3) f32
    const float* y = (const float*)d_in[1];   // (2, 4096, 3) f32
    float* out = (float*)d_out;               // 1 + 8192 + 8192 floats
    float* ws = (float*)d_ws;

    float* u2 = ws + WS_U;
    float* v2 = ws + WS_V;
    float* err = ws + WS_ERR;
    float* xs0 = ws + WS_SOA + 0 * NROWS;
    float* xs1 = ws + WS_SOA + 1 * NROWS;
    float* xs2 = ws + WS_SOA + 2 * NROWS;
    float* xn  = ws + WS_SOA + 3 * NROWS;
    float* ys0 = ws + WS_SOA + 4 * NROWS;
    float* ys1 = ws + WS_SOA + 5 * NROWS;
    float* ys2 = ws + WS_SOA + 6 * NROWS;
    float* yn  = ws + WS_SOA + 7 * NROWS;

    prep_kernel<<<32, 512, 0, stream>>>(x, y, ws, out);

    dim3 grid(NBLK), blk(THREADS);
    // i=0 (even): u2 = f(v2==0), err0
    lse_single<1, 1><<<grid, blk, 0, stream>>>(xs0, xs1, xs2, xn, ys0, ys1, ys2, yn,
                                               v2, u2, &err[0], nullptr, nullptr);
    // i=1 (odd): v2 = g(u2); frozen iff err0<T
    lse_single<0, 0><<<grid, blk, 0, stream>>>(ys0, ys1, ys2, yn, xs0, xs1, xs2, xn,
                                               u2, v2, nullptr, &err[0], nullptr);
    // i=2 (even): u2 = f(v2), err1; frozen iff err0<T
    lse_single<1, 0><<<grid, blk, 0, stream>>>(xs0, xs1, xs2, xn, ys0, ys1, ys2, yn,
                                               v2, u2, &err[1], &err[0], nullptr);
    // i=3 (odd): v2 = g(u2); frozen iff err0<T | err1<T (err1 stays 0 if frozen)
    lse_single<0, 0><<<grid, blk, 0, stream>>>(ys0, ys1, ys2, yn, xs0, xs1, xs2, xn,
                                               u2, v2, nullptr, &err[0], &err[1]);
    // i=4 fused into row_final (u_final == f(v_final) in every freeze case).
    row_final<<<grid, blk, 0, stream>>>(xs0, xs1, xs2, xn, ys0, ys1, ys2, yn,
                                        v2, u2, out + 1, out);
    col_final<<<grid, blk, 0, stream>>>(ys0, ys1, ys2, yn, xs0, xs1, xs2, xn,
                                        u2, out + 1 + NROWS);
}